// Round 3
// baseline (107.149 us; speedup 1.0000x reference)
//
#include <hip/hip_runtime.h>

#define BB 64
#define NN 64
#define TT 100
#define S_TOT (NN * TT)
#define WAVES_PER_BLOCK 4

// 4 waves per 256-thread block; wave w handles slice s = blockIdx.x*4 + w
// (s = t*NN + n). Thread b within the wave handles batch-agent b.
__global__ __launch_bounds__(256) void social_loss_kernel(
    const float* __restrict__ x,          // (B, N, T, 6) f32
    const float* __restrict__ wfa,        // (B, 3, 3)    f32
    const int* __restrict__ rand_idx,     // (T*N, B)     i32 in [0, B-2]
    const int* __restrict__ drop_mask,    // (T*N, B)     bool stored as i32
    float* __restrict__ out)              // (B, N) f32, pre-zeroed
{
    const int w = threadIdx.x >> 6;       // wave id 0..3
    const int b = threadIdx.x & 63;       // batch-agent 0..63
    const int s = blockIdx.x * WAVES_PER_BLOCK + w;   // 0..6399
    const int t = s >> 6;                 // NN == 64
    const int n = s & 63;

    // world_from_agent row-major (B,3,3): R = [:, :2, :2], trans = [:, :2, 2]
    const float* wp = wfa + b * 9;
    const float r00 = wp[0], r01 = wp[1], tx = wp[2];
    const float r10 = wp[3], r11 = wp[4], ty = wp[5];

    // pos = x[b, n, t, 0:2] — element offset (((b*NN+n)*TT)+t)*6 is even -> float2 aligned
    const size_t xoff = (((size_t)b * NN + n) * (size_t)TT + (size_t)t) * 6;
    const float2 p = *(const float2*)(x + xoff);

    // pos_g = R * p + trans
    const float gx = r00 * p.x + r01 * p.y + tx;
    const float gy = r10 * p.x + r11 * p.y + ty;
    const float sq = gx * gx + gy * gy;

    __shared__ float4 P[WAVES_PER_BLOCK][BB];
    P[w][b] = make_float4(gx, gy, sq, 0.0f);
    __syncthreads();

    // argmin_c dist[b,c], diagonal = inf, first-index tie rule via strict <
    float best = 3.4e38f;
    int besti = 0;
    #pragma unroll 16
    for (int c = 0; c < BB; ++c) {
        const float4 q = P[w][c];
        const float dot = fmaf(gx, q.x, gy * q.y);
        float d2 = fmaf(-2.0f, dot, sq + q.z);   // (sq_b + sq_c) - 2*dot, ref order
        d2 = fmaxf(d2, 1e-12f);
        if ((c != b) && (d2 < best)) { best = d2; besti = c; }
    }

    const size_t sb = (size_t)s * BB + b;
    const int r = rand_idx[sb];
    const int rnb = r + (r >= b ? 1 : 0);        // skip-self remap
    const int nb = drop_mask[sb] ? rnb : besti;

    const float4 q = P[w][nb];
    const float dot = fmaf(gx, q.x, gy * q.y);
    const float d2 = fmaxf(fmaf(-2.0f, dot, sq + q.z), 1e-12f);
    const float nd = sqrtf(d2);
    const float diff = nd - 1.5f;

    // loss[b,n] = mean_t (nd - 1.5)^2 ; 64 lanes -> 64 distinct cache lines
    atomicAdd(&out[b * NN + n], diff * diff * (1.0f / TT));
}

extern "C" void kernel_launch(void* const* d_in, const int* in_sizes, int n_in,
                              void* d_out, int out_size, void* d_ws, size_t ws_size,
                              hipStream_t stream) {
    const float* x = (const float*)d_in[0];
    const float* wfa = (const float*)d_in[1];
    const int* rand_idx = (const int*)d_in[2];
    const int* drop_mask = (const int*)d_in[3];
    float* out = (float*)d_out;

    // d_out is re-poisoned (0xAA) before every timed launch — zero it.
    hipMemsetAsync(out, 0, (size_t)out_size * sizeof(float), stream);

    social_loss_kernel<<<S_TOT / WAVES_PER_BLOCK, 256, 0, stream>>>(
        x, wfa, rand_idx, drop_mask, out);
}

// Round 4
// 79.428 us; speedup vs baseline: 1.3490x; 1.3490x over previous
//
#include <hip/hip_runtime.h>

#define BB 64
#define NN 64
#define TT 100
#define S_TOT (NN * TT)
#define WAVES_PER_BLOCK 4

// Kernel 1: 4 waves per 256-thread block; wave w handles slice s = blockIdx.x*4 + w
// (s = t*NN + n). Thread b handles batch-agent b. Plain store of diff^2 to
// ws[s*64+b] — no atomics (R3 showed 409,600 device-scope atomic RMWs onto 256
// cache lines wrote 12.8 MB to HBM and serialized the whole kernel).
__global__ __launch_bounds__(256) void social_slice_kernel(
    const float* __restrict__ x,          // (B, N, T, 6) f32
    const float* __restrict__ wfa,        // (B, 3, 3)    f32
    const int* __restrict__ rand_idx,     // (T*N, B)     i32 in [0, B-2]
    const int* __restrict__ drop_mask,    // (T*N, B)     bool stored as i32
    float* __restrict__ ws)               // (T*N, B) diff^2 partials
{
    const int w = threadIdx.x >> 6;       // wave id 0..3
    const int b = threadIdx.x & 63;       // batch-agent 0..63
    const int s = blockIdx.x * WAVES_PER_BLOCK + w;   // 0..6399
    const int t = s >> 6;                 // NN == 64
    const int n = s & 63;

    // world_from_agent row-major (B,3,3): R = [:, :2, :2], trans = [:, :2, 2]
    const float* wp = wfa + b * 9;
    const float r00 = wp[0], r01 = wp[1], tx = wp[2];
    const float r10 = wp[3], r11 = wp[4], ty = wp[5];

    // pos = x[b, n, t, 0:2] — element offset is even -> float2 aligned
    const size_t xoff = (((size_t)b * NN + n) * (size_t)TT + (size_t)t) * 6;
    const float2 p = *(const float2*)(x + xoff);

    // pos_g = R * p + trans
    const float gx = r00 * p.x + r01 * p.y + tx;
    const float gy = r10 * p.x + r11 * p.y + ty;
    const float sq = gx * gx + gy * gy;

    __shared__ float4 P[WAVES_PER_BLOCK][BB];
    P[w][b] = make_float4(gx, gy, sq, 0.0f);
    __syncthreads();

    // argmin_c dist[b,c], diagonal = inf, first-index tie rule via strict <
    float best = 3.4e38f;
    int besti = 0;
    #pragma unroll 16
    for (int c = 0; c < BB; ++c) {
        const float4 q = P[w][c];
        const float dot = fmaf(gx, q.x, gy * q.y);
        float d2 = fmaf(-2.0f, dot, sq + q.z);   // (sq_b + sq_c) - 2*dot, ref order
        d2 = fmaxf(d2, 1e-12f);
        if ((c != b) && (d2 < best)) { best = d2; besti = c; }
    }

    const size_t sb = (size_t)s * BB + b;
    const int r = rand_idx[sb];
    const int rnb = r + (r >= b ? 1 : 0);        // skip-self remap
    const int nb = drop_mask[sb] ? rnb : besti;

    const float4 q = P[w][nb];
    const float dot = fmaf(gx, q.x, gy * q.y);
    const float d2 = fmaxf(fmaf(-2.0f, dot, sq + q.z), 1e-12f);
    const float nd = sqrtf(d2);
    const float diff = nd - 1.5f;

    // disjoint per-wave region; lanes b contiguous -> coalesced 256 B store
    ws[sb] = diff * diff;
}

// Kernel 2: out[b,n] = (1/T) * sum_t ws[(t*NN+n)*BB + b].
// 16 blocks x 256 threads; lane = b -> contiguous reads (coalesced).
__global__ __launch_bounds__(256) void social_reduce_kernel(
    const float* __restrict__ ws,
    float* __restrict__ out)              // (B, N)
{
    const int b = threadIdx.x & 63;
    const int n = blockIdx.x * 4 + (threadIdx.x >> 6);

    float acc0 = 0.f, acc1 = 0.f, acc2 = 0.f, acc3 = 0.f;
    #pragma unroll 4
    for (int t = 0; t < TT; t += 4) {
        acc0 += ws[((t + 0) * NN + n) * BB + b];
        acc1 += ws[((t + 1) * NN + n) * BB + b];
        acc2 += ws[((t + 2) * NN + n) * BB + b];
        acc3 += ws[((t + 3) * NN + n) * BB + b];
    }
    out[b * NN + n] = ((acc0 + acc1) + (acc2 + acc3)) * (1.0f / TT);
}

extern "C" void kernel_launch(void* const* d_in, const int* in_sizes, int n_in,
                              void* d_out, int out_size, void* d_ws, size_t ws_size,
                              hipStream_t stream) {
    const float* x = (const float*)d_in[0];
    const float* wfa = (const float*)d_in[1];
    const int* rand_idx = (const int*)d_in[2];
    const int* drop_mask = (const int*)d_in[3];
    float* out = (float*)d_out;
    float* ws = (float*)d_ws;             // needs 6400*64*4 = 1.64 MB

    social_slice_kernel<<<S_TOT / WAVES_PER_BLOCK, 256, 0, stream>>>(
        x, wfa, rand_idx, drop_mask, ws);
    social_reduce_kernel<<<NN / 4, 256, 0, stream>>>(ws, out);
}

// Round 5
// 78.969 us; speedup vs baseline: 1.3568x; 1.0058x over previous
//
#include <hip/hip_runtime.h>

#define BB 64
#define NN 64
#define TT 100
#define S_TOT (NN * TT)
#define WAVES_PER_BLOCK 4

// Broadcast lane `lane`'s value of v to all 64 lanes via v_readlane (scalar
// dest, no LDS pipe, no sync needed — lanes of a wave are lockstep).
__device__ __forceinline__ float bcast(float v, int lane) {
    return __int_as_float(__builtin_amdgcn_readlane(__float_as_int(v), lane));
}

// Kernel 1: wave w of block handles slice s = blockIdx.x*4 + w (s = t*NN + n);
// lane b handles batch-agent b. All-pairs argmin done with readlane broadcasts
// (R4 profile: 64x ds_read_b128/thread put the loop on the LDS pipe, ~8 us/CU
// floor; readlane moves it to the VALU pipe, ~3 us floor, and removes the
// __syncthreads coupling entirely).
__global__ __launch_bounds__(256) void social_slice_kernel(
    const float* __restrict__ x,          // (B, N, T, 6) f32
    const float* __restrict__ wfa,        // (B, 3, 3)    f32
    const int* __restrict__ rand_idx,     // (T*N, B)     i32 in [0, B-2]
    const int* __restrict__ drop_mask,    // (T*N, B)     bool stored as i32
    float* __restrict__ ws)               // (T*N, B) diff^2 partials
{
    const int w = threadIdx.x >> 6;       // wave id 0..3
    const int b = threadIdx.x & 63;       // batch-agent 0..63
    const int s = blockIdx.x * WAVES_PER_BLOCK + w;   // 0..6399
    const int t = s >> 6;                 // NN == 64
    const int n = s & 63;

    // world_from_agent row-major (B,3,3): R = [:, :2, :2], trans = [:, :2, 2]
    const float* wp = wfa + b * 9;
    const float r00 = wp[0], r01 = wp[1], tx = wp[2];
    const float r10 = wp[3], r11 = wp[4], ty = wp[5];

    // pos = x[b, n, t, 0:2] — element offset is even -> float2 aligned
    const size_t xoff = (((size_t)b * NN + n) * (size_t)TT + (size_t)t) * 6;
    const float2 p = *(const float2*)(x + xoff);

    // pos_g = R * p + trans   (bit-identical to R4's passing arithmetic)
    const float gx = r00 * p.x + r01 * p.y + tx;
    const float gy = r10 * p.x + r11 * p.y + ty;
    const float sq = gx * gx + gy * gy;

    // argmin_c dist[b,c], diagonal excluded, first-index tie rule via strict <
    float best = 3.4e38f;
    int besti = 0;
    #pragma unroll
    for (int c = 0; c < BB; ++c) {
        const float qx = bcast(gx, c);
        const float qy = bcast(gy, c);
        const float qz = bcast(sq, c);
        const float dot = fmaf(gx, qx, gy * qy);
        float d2 = fmaf(-2.0f, dot, sq + qz);   // (sq_b + sq_c) - 2*dot, ref order
        d2 = fmaxf(d2, 1e-12f);
        const bool take = (c != b) && (d2 < best);
        best  = take ? d2 : best;
        besti = take ? c : besti;
    }

    const size_t sb = (size_t)s * BB + b;
    const int r = rand_idx[sb];
    const int rnb = r + (r >= b ? 1 : 0);        // skip-self remap (never == b)
    const int nb = drop_mask[sb] ? rnb : besti;

    // per-lane gather of neighbor's (gx,gy,sq): 3 bpermutes, once per slice
    const float qx = __shfl(gx, nb);
    const float qy = __shfl(gy, nb);
    const float qz = __shfl(sq, nb);
    const float dot = fmaf(gx, qx, gy * qy);
    const float d2 = fmaxf(fmaf(-2.0f, dot, sq + qz), 1e-12f);
    const float nd = sqrtf(d2);
    const float diff = nd - 1.5f;

    // disjoint per-wave region; lanes b contiguous -> coalesced 256 B store
    ws[sb] = diff * diff;
}

// Kernel 2: out[b,n] = (1/T) * sum_t ws[(t*NN+n)*BB + b].
// 16 blocks x 256 threads; lane = b -> contiguous reads (coalesced).
__global__ __launch_bounds__(256) void social_reduce_kernel(
    const float* __restrict__ ws,
    float* __restrict__ out)              // (B, N)
{
    const int b = threadIdx.x & 63;
    const int n = blockIdx.x * 4 + (threadIdx.x >> 6);

    float acc0 = 0.f, acc1 = 0.f, acc2 = 0.f, acc3 = 0.f;
    #pragma unroll 4
    for (int t = 0; t < TT; t += 4) {
        acc0 += ws[((t + 0) * NN + n) * BB + b];
        acc1 += ws[((t + 1) * NN + n) * BB + b];
        acc2 += ws[((t + 2) * NN + n) * BB + b];
        acc3 += ws[((t + 3) * NN + n) * BB + b];
    }
    out[b * NN + n] = ((acc0 + acc1) + (acc2 + acc3)) * (1.0f / TT);
}

extern "C" void kernel_launch(void* const* d_in, const int* in_sizes, int n_in,
                              void* d_out, int out_size, void* d_ws, size_t ws_size,
                              hipStream_t stream) {
    const float* x = (const float*)d_in[0];
    const float* wfa = (const float*)d_in[1];
    const int* rand_idx = (const int*)d_in[2];
    const int* drop_mask = (const int*)d_in[3];
    float* out = (float*)d_out;
    float* ws = (float*)d_ws;             // needs 6400*64*4 = 1.64 MB

    social_slice_kernel<<<S_TOT / WAVES_PER_BLOCK, 256, 0, stream>>>(
        x, wfa, rand_idx, drop_mask, ws);
    social_reduce_kernel<<<NN / 4, 256, 0, stream>>>(ws, out);
}

// Round 6
// 76.525 us; speedup vs baseline: 1.4002x; 1.0319x over previous
//
#include <hip/hip_runtime.h>

#define BB 64
#define NN 64
#define TT 100
#define TQ 4                  // consecutive t's per block
#define NTQ (TT / TQ)         // 25 t-chunks

// Broadcast lane `lane`'s value of v to all 64 lanes via v_readlane.
__device__ __forceinline__ float bcast(float v, int lane) {
    return __int_as_float(__builtin_amdgcn_readlane(__float_as_int(v), lane));
}

// Block = (n, t0..t0+3) tile, 256 threads / 4 waves.
// Phase 1 (coalesced): thread j stages x[b=j>>2, n, t0+(j&3), 0:2] -> transform -> LDS.
//   (R5 post-mortem: per-slice 64-line gather of x was the latency limiter;
//    this layout reads each x line once, ~30 sequential lines per instr.)
// Phase 2: wave w computes slice t = t0+w via readlane argmin (4 split chains for ILP).
// Phase 3: block combines its 4 t's, writes one partial row to ws.
__global__ __launch_bounds__(256) void social_slice_kernel(
    const float* __restrict__ x,          // (B, N, T, 6) f32
    const float* __restrict__ wfa,        // (B, 3, 3)    f32
    const int* __restrict__ rand_idx,     // (T*N, B)     i32 in [0, B-2]
    const int* __restrict__ drop_mask,    // (T*N, B)     bool stored as i32
    float* __restrict__ ws)               // (NTQ, NN, BB) 4-t partial sums
{
    const int n  = blockIdx.x & 63;       // grid = NTQ*64 blocks
    const int tq = blockIdx.x >> 6;       // 0..24
    const int t0 = tq * TQ;

    __shared__ float2 S[TQ][BB + 1];      // (gx,gy); +1 pad spreads write banks
    __shared__ float  Rld[TQ][BB];

    // ---- phase 1: coalesced load + transform ----
    {
        const int lb = threadIdx.x >> 2;  // 0..63
        const int k  = threadIdx.x & 3;   // 0..3
        const float* wp = wfa + lb * 9;
        const float r00 = wp[0], r01 = wp[1], tx = wp[2];
        const float r10 = wp[3], r11 = wp[4], ty = wp[5];
        const size_t xoff = (((size_t)lb * NN + n) * (size_t)TT + (size_t)(t0 + k)) * 6;
        const float2 p = *(const float2*)(x + xoff);   // even float offset -> 8B aligned
        const float gx = r00 * p.x + r01 * p.y + tx;   // same exprs as R5 (bit-identical)
        const float gy = r10 * p.x + r11 * p.y + ty;
        S[k][lb] = make_float2(gx, gy);
    }
    __syncthreads();

    // ---- phase 2: wave w handles slice t = t0 + w ----
    const int w = threadIdx.x >> 6;
    const int b = threadIdx.x & 63;
    const int t = t0 + w;
    const int s = t * NN + n;
    const size_t sb = (size_t)s * BB + b;
    const int r  = rand_idx[sb];          // coalesced, issued early
    const int dm = drop_mask[sb];

    const float2 g = S[w][b];
    const float gx = g.x, gy = g.y;
    const float sq = gx * gx + gy * gy;

    // argmin over c: 4 independent chains of 16 (contiguous c-ranges) -> 4x ILP
    // on the dependent select chain; in-order strict-< combine preserves the
    // reference first-index tie rule. Same fmaf ordering as R5 -> identical d2.
    float bd0 = 3.4e38f, bd1 = 3.4e38f, bd2 = 3.4e38f, bd3 = 3.4e38f;
    int   bi0 = 0, bi1 = 16, bi2 = 32, bi3 = 48;
    #pragma unroll
    for (int i = 0; i < 16; ++i) {
        {
            const int c = i;
            const float qx = bcast(gx, c), qy = bcast(gy, c), qz = bcast(sq, c);
            float d2 = fmaf(-2.0f, fmaf(gx, qx, gy * qy), sq + qz);
            d2 = fmaxf(d2, 1e-12f);
            const bool take = (c != b) && (d2 < bd0);
            bd0 = take ? d2 : bd0;  bi0 = take ? c : bi0;
        }
        {
            const int c = 16 + i;
            const float qx = bcast(gx, c), qy = bcast(gy, c), qz = bcast(sq, c);
            float d2 = fmaf(-2.0f, fmaf(gx, qx, gy * qy), sq + qz);
            d2 = fmaxf(d2, 1e-12f);
            const bool take = (c != b) && (d2 < bd1);
            bd1 = take ? d2 : bd1;  bi1 = take ? c : bi1;
        }
        {
            const int c = 32 + i;
            const float qx = bcast(gx, c), qy = bcast(gy, c), qz = bcast(sq, c);
            float d2 = fmaf(-2.0f, fmaf(gx, qx, gy * qy), sq + qz);
            d2 = fmaxf(d2, 1e-12f);
            const bool take = (c != b) && (d2 < bd2);
            bd2 = take ? d2 : bd2;  bi2 = take ? c : bi2;
        }
        {
            const int c = 48 + i;
            const float qx = bcast(gx, c), qy = bcast(gy, c), qz = bcast(sq, c);
            float d2 = fmaf(-2.0f, fmaf(gx, qx, gy * qy), sq + qz);
            d2 = fmaxf(d2, 1e-12f);
            const bool take = (c != b) && (d2 < bd3);
            bd3 = take ? d2 : bd3;  bi3 = take ? c : bi3;
        }
    }
    float best = bd0; int besti = bi0;
    if (bd1 < best) { best = bd1; besti = bi1; }
    if (bd2 < best) { best = bd2; besti = bi2; }
    if (bd3 < best) { best = bd3; besti = bi3; }

    const int rnb = r + (r >= b ? 1 : 0); // skip-self remap
    const int nb  = dm ? rnb : besti;

    const float qx = __shfl(gx, nb);
    const float qy = __shfl(gy, nb);
    const float qz = __shfl(sq, nb);
    const float dot = fmaf(gx, qx, gy * qy);
    const float d2m = fmaxf(fmaf(-2.0f, dot, sq + qz), 1e-12f);
    const float nd = sqrtf(d2m);
    const float diff = nd - 1.5f;
    Rld[w][b] = diff * diff;
    __syncthreads();

    // ---- phase 3: combine the block's 4 t's, one coalesced 256 B store ----
    if (w == 0) {
        const float sum4 = ((Rld[0][b] + Rld[1][b]) + Rld[2][b]) + Rld[3][b];
        ws[((size_t)tq * NN + n) * BB + b] = sum4;
    }
}

// out[b,n] = (1/T) * sum_tq ws[tq][n][b].  16 blocks x 256; lane=b coalesced.
__global__ __launch_bounds__(256) void social_reduce_kernel(
    const float* __restrict__ ws,
    float* __restrict__ out)              // (B, N)
{
    const int b = threadIdx.x & 63;
    const int n = blockIdx.x * 4 + (threadIdx.x >> 6);

    float acc = 0.f;
    #pragma unroll
    for (int tq = 0; tq < NTQ; ++tq)
        acc += ws[((size_t)tq * NN + n) * BB + b];
    out[b * NN + n] = acc * (1.0f / TT);
}

extern "C" void kernel_launch(void* const* d_in, const int* in_sizes, int n_in,
                              void* d_out, int out_size, void* d_ws, size_t ws_size,
                              hipStream_t stream) {
    const float* x = (const float*)d_in[0];
    const float* wfa = (const float*)d_in[1];
    const int* rand_idx = (const int*)d_in[2];
    const int* drop_mask = (const int*)d_in[3];
    float* out = (float*)d_out;
    float* ws = (float*)d_ws;             // needs 25*64*64*4 = 400 KB

    social_slice_kernel<<<NTQ * NN, 256, 0, stream>>>(
        x, wfa, rand_idx, drop_mask, ws);
    social_reduce_kernel<<<NN / 4, 256, 0, stream>>>(ws, out);
}